// Round 1
// baseline (3224.245 us; speedup 1.0000x reference)
//
#include <hip/hip_runtime.h>
#include <math.h>

#define SQ_EPS 1e-12f
#define BN_EPS 1e-5f

// ---------------- pooling: img(28x28) -> x2(14x14) -> x1(7x7) ----------------
__global__ void pool_kernel(const float* __restrict__ img,
                            float* __restrict__ x2, float* __restrict__ x1) {
    __shared__ float s_img[784];
    __shared__ float s_x2[196];
    int b = blockIdx.x;
    const float* im = img + b * 784;
    for (int i = threadIdx.x; i < 784; i += 256) s_img[i] = im[i];
    __syncthreads();
    for (int idx = threadIdx.x; idx < 196; idx += 256) {
        int i = idx / 14, j = idx % 14;
        float v = 0.25f * (s_img[(2*i)*28 + 2*j]     + s_img[(2*i)*28 + 2*j + 1] +
                           s_img[(2*i+1)*28 + 2*j]   + s_img[(2*i+1)*28 + 2*j + 1]);
        s_x2[idx] = v;
        x2[b*196 + idx] = v;
    }
    __syncthreads();
    for (int idx = threadIdx.x; idx < 49; idx += 256) {
        int i = idx / 7, j = idx % 7;
        float v = 0.25f * (s_x2[(2*i)*14 + 2*j]     + s_x2[(2*i)*14 + 2*j + 1] +
                           s_x2[(2*i+1)*14 + 2*j]   + s_x2[(2*i+1)*14 + 2*j + 1]);
        x1[b*49 + idx] = v;
    }
}

// ---------------- conv (1 in-ch, 128 out-ch, stride 1, VALID) + bias + relu ----------------
template<int IH, int IW, int KS, int OH, int OW>
__global__ __launch_bounds__(256) void conv_relu_kernel(
        const float* __restrict__ in, const float* __restrict__ w,
        const float* __restrict__ bias, float* __restrict__ y) {
    __shared__ float s_in[IH * IW];
    int b = blockIdx.x;
    const float* ip = in + b * IH * IW;
    for (int i = threadIdx.x; i < IH * IW; i += 256) s_in[i] = ip[i];
    __syncthreads();
    constexpr int OS = OH * OW;
    for (int idx = threadIdx.x; idx < 128 * OS; idx += 256) {
        int c = idx / OS, pos = idx % OS;
        int oi = pos / OW, oj = pos % OW;
        const float* wc = w + c * KS * KS;
        float acc = bias[c];
        #pragma unroll
        for (int u = 0; u < KS; ++u)
            #pragma unroll
            for (int v = 0; v < KS; ++v)
                acc += wc[u*KS + v] * s_in[(oi + u)*IW + oj + v];
        y[(b*128 + c)*OS + pos] = fmaxf(acc, 0.f);
    }
}

// ---------------- batchnorm stats -> scale/shift per channel ----------------
template<int S>   // spatial elems per (b, c); B=256, C=128
__global__ __launch_bounds__(256) void bn_stats_kernel(const float* __restrict__ y,
                                                       float* __restrict__ bnp) {
    int c = blockIdx.x;
    float sum = 0.f, sq = 0.f;
    for (int idx = threadIdx.x; idx < 256 * S; idx += 256) {
        int b = idx / S, s = idx % S;
        float v = y[(b*128 + c)*S + s];
        sum += v; sq += v * v;
    }
    for (int off = 32; off; off >>= 1) { sum += __shfl_down(sum, off); sq += __shfl_down(sq, off); }
    __shared__ float ssum[4], ssq[4];
    int lane = threadIdx.x & 63, wv = threadIdx.x >> 6;
    if (lane == 0) { ssum[wv] = sum; ssq[wv] = sq; }
    __syncthreads();
    if (threadIdx.x == 0) {
        float ts = ssum[0] + ssum[1] + ssum[2] + ssum[3];
        float tq = ssq[0] + ssq[1] + ssq[2] + ssq[3];
        const float N = 256.f * S;
        float mean = ts / N;
        float var = tq / N - mean * mean;
        float inv = rsqrtf(var + BN_EPS);
        bnp[c] = inv;              // scale
        bnp[128 + c] = -mean * inv; // shift
    }
}

// ---------------- primary caps conv as im2col GEMM (stride 2, VALID), BN fused on A-load ----------------
// out p[m][ch] = sum_k A[m][k] * W[ch][k] + pb[ch];  m=(b,si,sj), k=(c,u,v)
template<int S, int WO, int H, int W, int KS>
__global__ __launch_bounds__(256) void prim_gemm_kernel(
        const float* __restrict__ y, const float* __restrict__ wgt,
        const float* __restrict__ bnp, const float* __restrict__ pb,
        float* __restrict__ p) {
    constexpr int KK = KS * KS;
    constexpr int K  = 128 * KK;
    __shared__ float As[16][68];
    __shared__ float Bs[16][68];
    int bm = blockIdx.x * 64;
    int bn = blockIdx.y * 64;
    int tid = threadIdx.x;
    int tx = tid & 15, ty = tid >> 4;
    float acc[4][4] = {};
    // loader roles
    int kA = tid >> 4;            // 0..15
    int mA = (tid & 15) * 4;      // 0..60
    int chB = tid >> 2;           // 0..63
    int kB = (tid & 3) * 4;       // 0..12
    const float* wrow = wgt + (size_t)(bn + chB) * K;
    for (int kt = 0; kt < K; kt += 16) {
        {   // A tile: im2col gather + BN apply
            int kg = kt + kA;
            int c = kg / KK, rem = kg % KK;
            int u = rem / KS, v = rem % KS;
            float sc = bnp[c], sh = bnp[128 + c];
            const float* yc = y + c * (H * W) + u * W + v;
            #pragma unroll
            for (int t = 0; t < 4; ++t) {
                int m = bm + mA + t;
                int b = m / S, s = m % S;
                int si = s / WO, sj = s % WO;
                float val = yc[b * (128 * H * W) + (2 * si) * W + 2 * sj];
                As[kA][mA + t] = val * sc + sh;
            }
        }
        {   // B tile
            const float4 w4 = *(const float4*)(wrow + kt + kB);
            Bs[kB + 0][chB] = w4.x; Bs[kB + 1][chB] = w4.y;
            Bs[kB + 2][chB] = w4.z; Bs[kB + 3][chB] = w4.w;
        }
        __syncthreads();
        #pragma unroll
        for (int k = 0; k < 16; ++k) {
            float4 a  = *(const float4*)(&As[k][ty * 4]);
            float4 bb = *(const float4*)(&Bs[k][tx * 4]);
            float ar[4] = {a.x, a.y, a.z, a.w};
            float br[4] = {bb.x, bb.y, bb.z, bb.w};
            #pragma unroll
            for (int i = 0; i < 4; ++i)
                #pragma unroll
                for (int j = 0; j < 4; ++j)
                    acc[i][j] += ar[i] * br[j];
        }
        __syncthreads();
    }
    #pragma unroll
    for (int i = 0; i < 4; ++i) {
        int m = bm + ty * 4 + i;
        #pragma unroll
        for (int j = 0; j < 4; ++j) {
            int ch = bn + tx * 4 + j;
            p[(size_t)m * 256 + ch] = acc[i][j] + pb[ch];
        }
    }
}

// ---------------- squash primary caps: p(B*S,256) -> u(B,R=32*S,8) ----------------
template<int S>
__global__ void squash_primary_kernel(const float* __restrict__ p, float* __restrict__ u) {
    int idx = blockIdx.x * 256 + threadIdx.x;   // over B*32*S
    if (idx >= 256 * 32 * S) return;
    int b = idx / (32 * S), rem = idx % (32 * S);
    int o = rem / S, s = rem % S;
    const float* pp = p + (size_t)(b * S + s) * 256 + o;
    float t[8]; float sn = 0.f;
    #pragma unroll
    for (int i = 0; i < 8; ++i) { t[i] = pp[i * 32]; sn += t[i] * t[i]; }
    float f = sn / ((1.f + sn) * sqrtf(sn + SQ_EPS));
    float* up = u + (size_t)(b * (32 * S) + o * S + s) * 8;
    #pragma unroll
    for (int i = 0; i < 8; ++i) up[i] = t[i] * f;
}

// ---------------- dynamic routing (3 iters), priors recomputed on the fly ----------------
// grid (10, B); u:(B,R,8), rw:(10,R,8,16), lens:(B,10)
template<int R>
__global__ __launch_bounds__(256) void routing_kernel(
        const float* __restrict__ u, const float* __restrict__ rw,
        float* __restrict__ lens) {
    int n = blockIdx.x, b = blockIdx.y;
    const float* ub = u + (size_t)b * R * 8;
    const float* wn = rw + (size_t)n * R * 128;
    __shared__ float blog[R];
    __shared__ float red[4 * 16];
    __shared__ float vsh[16];
    __shared__ float sred[4];
    int tid = threadIdx.x, lane = tid & 63, wv = tid >> 6;
    for (int r = tid; r < R; r += 256) blog[r] = 0.f;
    __syncthreads();
    float v[16];
    for (int it = 0; it < 3; ++it) {
        // softmax over routes
        float lmax = -1e30f;
        for (int r = tid; r < R; r += 256) lmax = fmaxf(lmax, blog[r]);
        for (int off = 32; off; off >>= 1) lmax = fmaxf(lmax, __shfl_down(lmax, off));
        if (lane == 0) sred[wv] = lmax;
        __syncthreads();
        float mx = fmaxf(fmaxf(sred[0], sred[1]), fmaxf(sred[2], sred[3]));
        __syncthreads();
        float lsum = 0.f;
        for (int r = tid; r < R; r += 256) lsum += expf(blog[r] - mx);
        for (int off = 32; off; off >>= 1) lsum += __shfl_down(lsum, off);
        if (lane == 0) sred[wv] = lsum;
        __syncthreads();
        float inv = 1.f / (sred[0] + sred[1] + sred[2] + sred[3]);
        // pass A: s = sum_r c_r * prior_r
        float sacc[16] = {};
        for (int r = tid; r < R; r += 256) {
            float c = expf(blog[r] - mx) * inv;
            const float* uu = ub + (size_t)r * 8;
            const float* wr = wn + (size_t)r * 128;
            #pragma unroll
            for (int i = 0; i < 8; ++i) {
                float t = c * uu[i];
                #pragma unroll
                for (int o = 0; o < 16; ++o) sacc[o] += t * wr[i * 16 + o];
            }
        }
        #pragma unroll
        for (int o = 0; o < 16; ++o) {
            float xv = sacc[o];
            for (int off = 32; off; off >>= 1) xv += __shfl_down(xv, off);
            if (lane == 0) red[wv * 16 + o] = xv;
        }
        __syncthreads();
        if (tid < 16) vsh[tid] = red[tid] + red[16 + tid] + red[32 + tid] + red[48 + tid];
        __syncthreads();
        if (tid == 0) {
            float sn = 0.f;
            #pragma unroll
            for (int o = 0; o < 16; ++o) sn += vsh[o] * vsh[o];
            float f = sn / ((1.f + sn) * sqrtf(sn + SQ_EPS));
            #pragma unroll
            for (int o = 0; o < 16; ++o) vsh[o] *= f;
        }
        __syncthreads();
        #pragma unroll
        for (int o = 0; o < 16; ++o) v[o] = vsh[o];
        if (it < 2) {
            // pass B: blog_r += prior_r . v
            for (int r = tid; r < R; r += 256) {
                const float* uu = ub + (size_t)r * 8;
                const float* wr = wn + (size_t)r * 128;
                float dot = 0.f;
                #pragma unroll
                for (int i = 0; i < 8; ++i) {
                    float wi = 0.f;
                    #pragma unroll
                    for (int o = 0; o < 16; ++o) wi += wr[i * 16 + o] * v[o];
                    dot += uu[i] * wi;
                }
                blog[r] += dot;
            }
            __syncthreads();
        }
    }
    if (tid == 0) {
        float sn = 0.f;
        #pragma unroll
        for (int o = 0; o < 16; ++o) sn += v[o] * v[o];
        lens[b * 10 + n] = sqrtf(sn + SQ_EPS);
    }
}

// ---------------- final: softmax over classes of l1+l2+l3 ----------------
__global__ void final_softmax_kernel(const float* __restrict__ l1, const float* __restrict__ l2,
                                     const float* __restrict__ l3, float* __restrict__ out) {
    int b = threadIdx.x;  // 256 threads, 1 block
    float v[10]; float mx = -1e30f;
    #pragma unroll
    for (int n = 0; n < 10; ++n) {
        v[n] = l1[b * 10 + n] + l2[b * 10 + n] + l3[b * 10 + n];
        mx = fmaxf(mx, v[n]);
    }
    float s = 0.f;
    #pragma unroll
    for (int n = 0; n < 10; ++n) { v[n] = expf(v[n] - mx); s += v[n]; }
    float inv = 1.f / s;
    #pragma unroll
    for (int n = 0; n < 10; ++n) out[b * 10 + n] = v[n] * inv;
}

extern "C" void kernel_launch(void* const* d_in, const int* in_sizes, int n_in,
                              void* d_out, int out_size, void* d_ws, size_t ws_size,
                              hipStream_t stream) {
    const float* x   = (const float*)d_in[0];
    const float* c1w = (const float*)d_in[1];
    const float* c1b = (const float*)d_in[2];
    const float* p1w = (const float*)d_in[3];
    const float* p1b = (const float*)d_in[4];
    const float* d1w = (const float*)d_in[5];
    const float* c2w = (const float*)d_in[6];
    const float* c2b = (const float*)d_in[7];
    const float* p2w = (const float*)d_in[8];
    const float* p2b = (const float*)d_in[9];
    const float* d2w = (const float*)d_in[10];
    const float* c3w = (const float*)d_in[11];
    const float* c3b = (const float*)d_in[12];
    const float* p3w = (const float*)d_in[13];
    const float* p3b = (const float*)d_in[14];
    const float* d3w = (const float*)d_in[15];

    float* ws = (float*)d_ws;
    float* x2   = ws;                    // 256*196
    float* x1   = x2 + 50176;            // 256*49
    float* y1   = x1 + 12544;            // 256*128*25
    float* y2   = y1 + 819200;           // 256*128*100
    float* y3   = y2 + 3276800;          // 256*128*400
    float* p1   = y3 + 13107200;         // 1024*256
    float* p2   = p1 + 262144;           // 2304*256
    float* p3   = p2 + 589824;           // 9216*256
    float* u1   = p3 + 2359296;          // 256*128*8
    float* u2   = u1 + 262144;           // 256*288*8
    float* u3   = u2 + 589824;           // 256*1152*8
    float* bnp1 = u3 + 2359296;          // 256
    float* bnp2 = bnp1 + 256;
    float* bnp3 = bnp2 + 256;
    float* l1   = bnp3 + 256;            // 2560 each
    float* l2   = l1 + 2560;
    float* l3   = l2 + 2560;

    pool_kernel<<<256, 256, 0, stream>>>(x, x2, x1);

    conv_relu_kernel<7, 7, 3, 5, 5><<<256, 256, 0, stream>>>(x1, c1w, c1b, y1);
    conv_relu_kernel<14, 14, 5, 10, 10><<<256, 256, 0, stream>>>(x2, c2w, c2b, y2);
    conv_relu_kernel<28, 28, 9, 20, 20><<<256, 256, 0, stream>>>(x, c3w, c3b, y3);

    bn_stats_kernel<25><<<128, 256, 0, stream>>>(y1, bnp1);
    bn_stats_kernel<100><<<128, 256, 0, stream>>>(y2, bnp2);
    bn_stats_kernel<400><<<128, 256, 0, stream>>>(y3, bnp3);

    prim_gemm_kernel<4, 2, 5, 5, 3><<<dim3(16, 4), 256, 0, stream>>>(y1, p1w, bnp1, p1b, p1);
    prim_gemm_kernel<9, 3, 10, 10, 5><<<dim3(36, 4), 256, 0, stream>>>(y2, p2w, bnp2, p2b, p2);
    prim_gemm_kernel<36, 6, 20, 20, 9><<<dim3(144, 4), 256, 0, stream>>>(y3, p3w, bnp3, p3b, p3);

    squash_primary_kernel<4><<<128, 256, 0, stream>>>(p1, u1);
    squash_primary_kernel<9><<<288, 256, 0, stream>>>(p2, u2);
    squash_primary_kernel<36><<<1152, 256, 0, stream>>>(p3, u3);

    routing_kernel<128><<<dim3(10, 256), 256, 0, stream>>>(u1, d1w, l1);
    routing_kernel<288><<<dim3(10, 256), 256, 0, stream>>>(u2, d2w, l2);
    routing_kernel<1152><<<dim3(10, 256), 256, 0, stream>>>(u3, d3w, l3);

    final_softmax_kernel<<<1, 256, 0, stream>>>(l1, l2, l3, (float*)d_out);
}

// Round 3
// 954.423 us; speedup vs baseline: 3.3782x; 3.3782x over previous
//
#include <hip/hip_runtime.h>
#include <math.h>

#define SQ_EPS 1e-12f
#define BN_EPS 1e-5f

typedef short short8 __attribute__((ext_vector_type(8)));
typedef float f32x4 __attribute__((ext_vector_type(4)));
typedef unsigned short ushort_t;

__device__ inline unsigned short f2bf(float x) {
    unsigned int u = __float_as_uint(x);
    unsigned int r = (u + 0x7fffu + ((u >> 16) & 1u)) >> 16;   // round-to-nearest-even
    return (unsigned short)r;
}
__device__ inline float bf2f(unsigned short h) {
    return __uint_as_float(((unsigned int)h) << 16);
}

// ---------------- pooling: img(28x28) -> x2(14x14) -> x1(7x7) ----------------
__global__ void pool_kernel(const float* __restrict__ img,
                            float* __restrict__ x2, float* __restrict__ x1) {
    __shared__ float s_img[784];
    __shared__ float s_x2[196];
    int b = blockIdx.x;
    const float* im = img + b * 784;
    for (int i = threadIdx.x; i < 784; i += 256) s_img[i] = im[i];
    __syncthreads();
    for (int idx = threadIdx.x; idx < 196; idx += 256) {
        int i = idx / 14, j = idx % 14;
        float v = 0.25f * (s_img[(2*i)*28 + 2*j]     + s_img[(2*i)*28 + 2*j + 1] +
                           s_img[(2*i+1)*28 + 2*j]   + s_img[(2*i+1)*28 + 2*j + 1]);
        s_x2[idx] = v;
        x2[b*196 + idx] = v;
    }
    __syncthreads();
    for (int idx = threadIdx.x; idx < 49; idx += 256) {
        int i = idx / 7, j = idx % 7;
        float v = 0.25f * (s_x2[(2*i)*14 + 2*j]     + s_x2[(2*i)*14 + 2*j + 1] +
                           s_x2[(2*i+1)*14 + 2*j]   + s_x2[(2*i+1)*14 + 2*j + 1]);
        x1[b*49 + idx] = v;
    }
}

// ---------------- zero bn accumulators (ws is poisoned each launch) ----------------
__global__ void zero_bnp_kernel(float* __restrict__ bnp_base) {
    bnp_base[blockIdx.x * 512 + threadIdx.x] = 0.f;  // zero sum[128] + sq[128]
}

// ---------------- conv (1->128ch, stride1, VALID) + relu, fused:
//   * output written as split bf16 (hi+lo), layout [b][pos][c] (c innermost)
//   * per-channel sum/sumsq accumulated via atomics for BN
template<int IH, int IW, int KS, int OH, int OW>
__global__ __launch_bounds__(256) void conv_split_kernel(
        const float* __restrict__ in, const float* __restrict__ w,
        const float* __restrict__ bias,
        ushort_t* __restrict__ yh, ushort_t* __restrict__ yl,
        float* __restrict__ bnp) {
    constexpr int KK = KS * KS;
    constexpr int OS = OH * OW;
    __shared__ float s_img[IH * IW];
    __shared__ float s_w[128 * KK];
    __shared__ float s_red[256];
    int b = blockIdx.x, tid = threadIdx.x;
    const float* ip = in + b * IH * IW;
    for (int i = tid; i < IH * IW; i += 256) s_img[i] = ip[i];
    for (int i = tid; i < 128 * KK; i += 256) s_w[i] = w[i];
    __syncthreads();
    int c = tid & 127, half = tid >> 7;
    float bias_c = bias[c];
    float bsum = 0.f, bsq = 0.f;
    for (int r = half; r < OH; r += 2) {
        float acc[OW];
        #pragma unroll
        for (int j = 0; j < OW; ++j) acc[j] = bias_c;
        for (int u = 0; u < KS; ++u) {
            float rg[OW + KS - 1];
            #pragma unroll
            for (int j = 0; j < OW + KS - 1; ++j) rg[j] = s_img[(r + u) * IW + j];
            #pragma unroll
            for (int v = 0; v < KS; ++v) {
                float wv = s_w[c * KK + u * KS + v];
                #pragma unroll
                for (int j = 0; j < OW; ++j) acc[j] += wv * rg[j + v];
            }
        }
        #pragma unroll
        for (int j = 0; j < OW; ++j) {
            float val = fmaxf(acc[j], 0.f);
            bsum += val; bsq += val * val;
            unsigned short h = f2bf(val);
            unsigned short lo = f2bf(val - bf2f(h));
            int oidx = ((b * OS) + r * OW + j) * 128 + c;
            yh[oidx] = h; yl[oidx] = lo;
        }
    }
    s_red[tid] = bsum; __syncthreads();
    if (tid < 128) atomicAdd(&bnp[c], s_red[tid] + s_red[tid + 128]);
    __syncthreads();
    s_red[tid] = bsq; __syncthreads();
    if (tid < 128) atomicAdd(&bnp[128 + c], s_red[tid] + s_red[tid + 128]);
}

// ---------------- finalize BN: scale/shift per channel, 3 branches ----------------
__global__ void bn_final_kernel(float* __restrict__ bnp_base) {
    int br = blockIdx.x;
    float* bnp = bnp_base + br * 512;
    float N = (br == 0) ? 6400.f : ((br == 1) ? 25600.f : 102400.f);
    int c = threadIdx.x;  // 128
    float mean = bnp[c] / N;
    float var = bnp[128 + c] / N - mean * mean;
    float inv = rsqrtf(var + BN_EPS);
    bnp[256 + c] = inv;
    bnp[384 + c] = -mean * inv;
}

// ---------------- weight transform: W[ch][c][uv]*scale_c -> split bf16 [uv][ch][c] ----------------
template<int KK>
__global__ void wtrans_kernel(const float* __restrict__ w, const float* __restrict__ bnp,
                              ushort_t* __restrict__ wh, ushort_t* __restrict__ wl) {
    int idx = blockIdx.x * 256 + threadIdx.x;   // KK*256*128 total
    int c = idx & 127, ch = (idx >> 7) & 255, uv = idx >> 15;
    float val = w[((ch << 7) + c) * KK + uv] * bnp[256 + c];
    unsigned short h = f2bf(val);
    unsigned short lo = f2bf(val - bf2f(h));
    wh[idx] = h; wl[idx] = lo;
}

// ---------------- fold BN shift into per-channel bias: bias'[ch]=pb[ch]+sum_k shift_c*W[ch][k] ----------------
template<int KK>
__global__ void biasfold_kernel(const float* __restrict__ w, const float* __restrict__ bnp,
                                const float* __restrict__ pb, float* __restrict__ biasf) {
    int ch = blockIdx.x, tid = threadIdx.x;  // 128 threads, c = tid
    const float* wrow = w + (ch * 128 + tid) * KK;
    float s = 0.f;
    for (int uv = 0; uv < KK; ++uv) s += wrow[uv];
    s *= bnp[384 + tid];
    for (int off = 32; off; off >>= 1) s += __shfl_down(s, off);
    __shared__ float r2[2];
    if ((tid & 63) == 0) r2[tid >> 6] = s;
    __syncthreads();
    if (tid == 0) biasf[ch] = pb[ch] + r2[0] + r2[1];
}

// ---------------- primary-caps conv as split-bf16 MFMA GEMM ----------------
// p[m][ch] = sum_{uv,c} y[b, 2si+u, 2sj+v, c] * W'[uv][ch][c] + bias'[ch]
// block tile 128(M) x 64(N), 4 waves as 2x2, per-wave 64x32 (4x2 of 16x16), BK=32
template<int S, int WO, int IHg, int IWg, int KS>
__global__ __launch_bounds__(256, 2) void prim_gemm_mfma(
        const ushort_t* __restrict__ yh, const ushort_t* __restrict__ yl,
        const ushort_t* __restrict__ wh, const ushort_t* __restrict__ wl,
        const float* __restrict__ biasf, float* __restrict__ p) {
    constexpr int KK = KS * KS;
    constexpr int AP = 40;   // LDS row pitch in halves (32 + 8 pad, keeps 16B alignment)
    __shared__ ushort_t Ash[128 * AP], Asl[128 * AP];
    __shared__ ushort_t Bsh[64 * AP],  Bsl[64 * AP];
    int tid = threadIdx.x;
    int bm = blockIdx.x * 128, ch0 = blockIdx.y * 64;
    // ---- staging roles
    int arow0 = tid >> 2, arow1 = arow0 + 64;
    int cpart = (tid & 3) * 8;
    int m0 = bm + arow0;
    int b0 = m0 / S, s0 = m0 % S;
    int abase0 = ((b0 * IHg + 2 * (s0 / WO)) * IWg + 2 * (s0 % WO)) * 128 + cpart;
    int m1 = bm + arow1;
    int b1 = m1 / S, s1 = m1 % S;
    int abase1 = ((b1 * IHg + 2 * (s1 / WO)) * IWg + 2 * (s1 % WO)) * 128 + cpart;
    int bbase = (ch0 + (tid >> 2)) * 128 + cpart;
    int awL0 = arow0 * AP + cpart;
    int awL1 = arow1 * AP + cpart;
    int bwL  = (tid >> 2) * AP + cpart;
    // ---- compute roles
    int lane = tid & 63, wid = tid >> 6;
    int wm = wid & 1, wn = wid >> 1;
    int quad = lane >> 4, l16 = lane & 15;
    int aoffL[4], boffL[2];
    #pragma unroll
    for (int mi = 0; mi < 4; ++mi) aoffL[mi] = (wm * 64 + mi * 16 + l16) * AP + quad * 8;
    #pragma unroll
    for (int ni = 0; ni < 2; ++ni) boffL[ni] = (wn * 32 + ni * 16 + l16) * AP + quad * 8;
    f32x4 acc[4][2];
    #pragma unroll
    for (int mi = 0; mi < 4; ++mi)
        #pragma unroll
        for (int ni = 0; ni < 2; ++ni)
            acc[mi][ni] = (f32x4){0.f, 0.f, 0.f, 0.f};

    for (int u = 0; u < KS; ++u) {
        for (int v = 0; v < KS; ++v) {
            int aoff = (u * IWg + v) * 128;
            int boff = (u * KS + v) * 32768;
            for (int cs = 0; cs < 128; cs += 32) {
                int4 a0h = *reinterpret_cast<const int4*>(yh + abase0 + aoff + cs);
                int4 a0l = *reinterpret_cast<const int4*>(yl + abase0 + aoff + cs);
                int4 a1h = *reinterpret_cast<const int4*>(yh + abase1 + aoff + cs);
                int4 a1l = *reinterpret_cast<const int4*>(yl + abase1 + aoff + cs);
                int4 b4h = *reinterpret_cast<const int4*>(wh + bbase + boff + cs);
                int4 b4l = *reinterpret_cast<const int4*>(wl + bbase + boff + cs);
                __syncthreads();
                *reinterpret_cast<int4*>(&Ash[awL0]) = a0h;
                *reinterpret_cast<int4*>(&Asl[awL0]) = a0l;
                *reinterpret_cast<int4*>(&Ash[awL1]) = a1h;
                *reinterpret_cast<int4*>(&Asl[awL1]) = a1l;
                *reinterpret_cast<int4*>(&Bsh[bwL]) = b4h;
                *reinterpret_cast<int4*>(&Bsl[bwL]) = b4l;
                __syncthreads();
                short8 ah[4], al[4], bh[2], bl[2];
                #pragma unroll
                for (int mi = 0; mi < 4; ++mi) {
                    ah[mi] = *reinterpret_cast<const short8*>(&Ash[aoffL[mi]]);
                    al[mi] = *reinterpret_cast<const short8*>(&Asl[aoffL[mi]]);
                }
                #pragma unroll
                for (int ni = 0; ni < 2; ++ni) {
                    bh[ni] = *reinterpret_cast<const short8*>(&Bsh[boffL[ni]]);
                    bl[ni] = *reinterpret_cast<const short8*>(&Bsl[boffL[ni]]);
                }
                #pragma unroll
                for (int mi = 0; mi < 4; ++mi)
                    #pragma unroll
                    for (int ni = 0; ni < 2; ++ni) {
                        acc[mi][ni] = __builtin_amdgcn_mfma_f32_16x16x32_bf16(ah[mi], bh[ni], acc[mi][ni], 0, 0, 0);
                        acc[mi][ni] = __builtin_amdgcn_mfma_f32_16x16x32_bf16(al[mi], bh[ni], acc[mi][ni], 0, 0, 0);
                        acc[mi][ni] = __builtin_amdgcn_mfma_f32_16x16x32_bf16(ah[mi], bl[ni], acc[mi][ni], 0, 0, 0);
                    }
            }
        }
    }
    float bv[2];
    #pragma unroll
    for (int ni = 0; ni < 2; ++ni) bv[ni] = biasf[ch0 + wn * 32 + ni * 16 + l16];
    #pragma unroll
    for (int mi = 0; mi < 4; ++mi)
        #pragma unroll
        for (int ni = 0; ni < 2; ++ni) {
            int col = ch0 + wn * 32 + ni * 16 + l16;
            #pragma unroll
            for (int reg = 0; reg < 4; ++reg) {
                int row = bm + wm * 64 + mi * 16 + quad * 4 + reg;
                p[(size_t)row * 256 + col] = acc[mi][ni][reg] + bv[ni];
            }
        }
}

// ---------------- squash primary caps: p(B*S,256) -> u(B,R=32*S,8) ----------------
template<int S>
__global__ void squash_primary_kernel(const float* __restrict__ p, float* __restrict__ u) {
    int idx = blockIdx.x * 256 + threadIdx.x;   // over B*32*S
    if (idx >= 256 * 32 * S) return;
    int b = idx / (32 * S), rem = idx % (32 * S);
    int o = rem / S, s = rem % S;
    const float* pp = p + (size_t)(b * S + s) * 256 + o;
    float t[8]; float sn = 0.f;
    #pragma unroll
    for (int i = 0; i < 8; ++i) { t[i] = pp[i * 32]; sn += t[i] * t[i]; }
    float f = sn / ((1.f + sn) * sqrtf(sn + SQ_EPS));
    float* up = u + (size_t)(b * (32 * S) + o * S + s) * 8;
    #pragma unroll
    for (int i = 0; i < 8; ++i) up[i] = t[i] * f;
}

// ---------------- dynamic routing (3 iters), priors cached in LDS (bf16) ----------------
template<int R>
__global__ __launch_bounds__(256) void routing_kernel(
        const float* __restrict__ u, const float* __restrict__ rw,
        float* __restrict__ lens) {
    int n = blockIdx.x, b = blockIdx.y;
    __shared__ ushort_t pri[R * 17];
    __shared__ float blog[R];
    __shared__ float red[4 * 16];
    __shared__ float vsh[16];
    __shared__ float sred[4];
    int tid = threadIdx.x, lane = tid & 63, wv = tid >> 6;
    // compute priors once: prior[r][o] = sum_i u[b][r][i] * rw[n][r][i][o]
    for (int r = tid; r < R; r += 256) {
        const float4* up = (const float4*)(u + ((size_t)b * R + r) * 8);
        float4 ua = up[0], ub = up[1];
        float uu[8] = {ua.x, ua.y, ua.z, ua.w, ub.x, ub.y, ub.z, ub.w};
        const float4* wp = (const float4*)(rw + ((size_t)n * R + r) * 128);
        float po[16] = {};
        #pragma unroll
        for (int i = 0; i < 8; ++i) {
            #pragma unroll
            for (int o4 = 0; o4 < 4; ++o4) {
                float4 w4 = wp[i * 4 + o4];
                po[o4 * 4 + 0] += uu[i] * w4.x;
                po[o4 * 4 + 1] += uu[i] * w4.y;
                po[o4 * 4 + 2] += uu[i] * w4.z;
                po[o4 * 4 + 3] += uu[i] * w4.w;
            }
        }
        #pragma unroll
        for (int o = 0; o < 16; ++o) pri[r * 17 + o] = f2bf(po[o]);
        blog[r] = 0.f;
    }
    __syncthreads();
    float v[16];
    for (int it = 0; it < 3; ++it) {
        float lmax = -1e30f;
        for (int r = tid; r < R; r += 256) lmax = fmaxf(lmax, blog[r]);
        for (int off = 32; off; off >>= 1) lmax = fmaxf(lmax, __shfl_down(lmax, off));
        if (lane == 0) sred[wv] = lmax;
        __syncthreads();
        float mx = fmaxf(fmaxf(sred[0], sred[1]), fmaxf(sred[2], sred[3]));
        __syncthreads();
        float lsum = 0.f;
        for (int r = tid; r < R; r += 256) lsum += expf(blog[r] - mx);
        for (int off = 32; off; off >>= 1) lsum += __shfl_down(lsum, off);
        if (lane == 0) sred[wv] = lsum;
        __syncthreads();
        float inv = 1.f / (sred[0] + sred[1] + sred[2] + sred[3]);
        float sacc[16] = {};
        for (int r = tid; r < R; r += 256) {
            float c = expf(blog[r] - mx) * inv;
            #pragma unroll
            for (int o = 0; o < 16; ++o) sacc[o] += c * bf2f(pri[r * 17 + o]);
        }
        #pragma unroll
        for (int o = 0; o < 16; ++o) {
            float xv = sacc[o];
            for (int off = 32; off; off >>= 1) xv += __shfl_down(xv, off);
            if (lane == 0) red[wv * 16 + o] = xv;
        }
        __syncthreads();
        if (tid < 16) vsh[tid] = red[tid] + red[16 + tid] + red[32 + tid] + red[48 + tid];
        __syncthreads();
        if (tid == 0) {
            float sn = 0.f;
            #pragma unroll
            for (int o = 0; o < 16; ++o) sn += vsh[o] * vsh[o];
            float f = sn / ((1.f + sn) * sqrtf(sn + SQ_EPS));
            #pragma unroll
            for (int o = 0; o < 16; ++o) vsh[o] *= f;
        }
        __syncthreads();
        #pragma unroll
        for (int o = 0; o < 16; ++o) v[o] = vsh[o];
        if (it < 2) {
            for (int r = tid; r < R; r += 256) {
                float dot = 0.f;
                #pragma unroll
                for (int o = 0; o < 16; ++o) dot += bf2f(pri[r * 17 + o]) * v[o];
                blog[r] += dot;
            }
            __syncthreads();
        }
    }
    if (tid == 0) {
        float sn = 0.f;
        #pragma unroll
        for (int o = 0; o < 16; ++o) sn += v[o] * v[o];
        lens[b * 10 + n] = sqrtf(sn + SQ_EPS);
    }
}

// ---------------- final: softmax over classes of l1+l2+l3 ----------------
__global__ void final_softmax_kernel(const float* __restrict__ l1, const float* __restrict__ l2,
                                     const float* __restrict__ l3, float* __restrict__ out) {
    int b = threadIdx.x;
    float v[10]; float mx = -1e30f;
    #pragma unroll
    for (int n = 0; n < 10; ++n) {
        v[n] = l1[b * 10 + n] + l2[b * 10 + n] + l3[b * 10 + n];
        mx = fmaxf(mx, v[n]);
    }
    float s = 0.f;
    #pragma unroll
    for (int n = 0; n < 10; ++n) { v[n] = expf(v[n] - mx); s += v[n]; }
    float inv = 1.f / s;
    #pragma unroll
    for (int n = 0; n < 10; ++n) out[b * 10 + n] = v[n] * inv;
}

extern "C" void kernel_launch(void* const* d_in, const int* in_sizes, int n_in,
                              void* d_out, int out_size, void* d_ws, size_t ws_size,
                              hipStream_t stream) {
    const float* x   = (const float*)d_in[0];
    const float* c1w = (const float*)d_in[1];
    const float* c1b = (const float*)d_in[2];
    const float* p1w = (const float*)d_in[3];
    const float* p1b = (const float*)d_in[4];
    const float* d1w = (const float*)d_in[5];
    const float* c2w = (const float*)d_in[6];
    const float* c2b = (const float*)d_in[7];
    const float* p2w = (const float*)d_in[8];
    const float* p2b = (const float*)d_in[9];
    const float* d2w = (const float*)d_in[10];
    const float* c3w = (const float*)d_in[11];
    const float* c3b = (const float*)d_in[12];
    const float* p3w = (const float*)d_in[13];
    const float* p3b = (const float*)d_in[14];
    const float* d3w = (const float*)d_in[15];

    float* ws = (float*)d_ws;
    // region layout (float units) — total 23,403,520 floats = 93.6 MB
    float* x2    = ws + 0;          // 50176
    float* x1    = ws + 50176;      // 12544
    float* yh1f  = ws + 62720;      // 409600   (819200 halves)  [aliased by u1 later]
    float* yl1f  = ws + 472320;     // 409600
    float* yh2f  = ws + 881920;     // 1638400  [aliased by u2 later]
    float* yl2f  = ws + 2520320;    // 1638400
    float* yh3f  = ws + 4158720;    // 6553600  [aliased by u3 later]
    float* yl3f  = ws + 10712320;   // 6553600
    float* wh1f  = ws + 17265920;   // 147456
    float* wl1f  = ws + 17413376;   // 147456
    float* wh2f  = ws + 17560832;   // 409600
    float* wl2f  = ws + 17970432;   // 409600
    float* wh3f  = ws + 18380032;   // 1327104  [aliased by p2 later]
    float* wl3f  = ws + 19707136;   // 1327104  [aliased by p1 later]
    float* p3    = ws + 21034240;   // 2359296
    float* bnp1  = ws + 23393536;   // 512
    float* bnp2  = ws + 23394048;   // 512
    float* bnp3  = ws + 23394560;   // 512
    float* bias1 = ws + 23395072;   // 256
    float* bias2 = ws + 23395328;   // 256
    float* bias3 = ws + 23395584;   // 256
    float* l1    = ws + 23395840;   // 2560
    float* l2    = ws + 23398400;   // 2560
    float* l3    = ws + 23400960;   // 2560

    ushort_t* yh1 = (ushort_t*)yh1f; ushort_t* yl1 = (ushort_t*)yl1f;
    ushort_t* yh2 = (ushort_t*)yh2f; ushort_t* yl2 = (ushort_t*)yl2f;
    ushort_t* yh3 = (ushort_t*)yh3f; ushort_t* yl3 = (ushort_t*)yl3f;
    ushort_t* wh1 = (ushort_t*)wh1f; ushort_t* wl1 = (ushort_t*)wl1f;
    ushort_t* wh2 = (ushort_t*)wh2f; ushort_t* wl2 = (ushort_t*)wl2f;
    ushort_t* wh3 = (ushort_t*)wh3f; ushort_t* wl3 = (ushort_t*)wl3f;
    // aliases (safe by stream ordering):
    float* u1 = yh1f;   // 262144 <= 409600, written after gemm1 reads yh1
    float* u2 = yh2f;   // 589824 <= 1638400
    float* u3 = yh3f;   // 2359296 <= 6553600
    float* p2 = wh3f;   // 589824 <= 1327104, written after gemm3 reads wh3
    float* p1 = wl3f;   // 262144 <= 1327104

    pool_kernel<<<256, 256, 0, stream>>>(x, x2, x1);
    zero_bnp_kernel<<<3, 256, 0, stream>>>(bnp1);

    conv_split_kernel<7, 7, 3, 5, 5><<<256, 256, 0, stream>>>(x1, c1w, c1b, yh1, yl1, bnp1);
    conv_split_kernel<14, 14, 5, 10, 10><<<256, 256, 0, stream>>>(x2, c2w, c2b, yh2, yl2, bnp2);
    conv_split_kernel<28, 28, 9, 20, 20><<<256, 256, 0, stream>>>(x, c3w, c3b, yh3, yl3, bnp3);

    bn_final_kernel<<<3, 128, 0, stream>>>(bnp1);

    wtrans_kernel<9><<<1152, 256, 0, stream>>>(p1w, bnp1, wh1, wl1);
    wtrans_kernel<25><<<3200, 256, 0, stream>>>(p2w, bnp2, wh2, wl2);
    wtrans_kernel<81><<<10368, 256, 0, stream>>>(p3w, bnp3, wh3, wl3);

    biasfold_kernel<9><<<256, 128, 0, stream>>>(p1w, bnp1, p1b, bias1);
    biasfold_kernel<25><<<256, 128, 0, stream>>>(p2w, bnp2, p2b, bias2);
    biasfold_kernel<81><<<256, 128, 0, stream>>>(p3w, bnp3, p3b, bias3);

    // gemm3 first: afterwards wh3/wl3 are dead and reused for p2/p1
    prim_gemm_mfma<36, 6, 20, 20, 9><<<dim3(72, 4), 256, 0, stream>>>(yh3, yl3, wh3, wl3, bias3, p3);
    prim_gemm_mfma<9, 3, 10, 10, 5><<<dim3(18, 4), 256, 0, stream>>>(yh2, yl2, wh2, wl2, bias2, p2);
    prim_gemm_mfma<4, 2, 5, 5, 3><<<dim3(8, 4), 256, 0, stream>>>(yh1, yl1, wh1, wl1, bias1, p1);

    squash_primary_kernel<36><<<1152, 256, 0, stream>>>(p3, u3);
    squash_primary_kernel<9><<<288, 256, 0, stream>>>(p2, u2);
    squash_primary_kernel<4><<<128, 256, 0, stream>>>(p1, u1);

    routing_kernel<128><<<dim3(10, 256), 256, 0, stream>>>(u1, d1w, l1);
    routing_kernel<288><<<dim3(10, 256), 256, 0, stream>>>(u2, d2w, l2);
    routing_kernel<1152><<<dim3(10, 256), 256, 0, stream>>>(u3, d3w, l3);

    final_softmax_kernel<<<1, 256, 0, stream>>>(l1, l2, l3, (float*)d_out);
}

// Round 5
// 893.905 us; speedup vs baseline: 3.6069x; 1.0677x over previous
//
#include <hip/hip_runtime.h>
#include <math.h>

#define SQ_EPS 1e-12f
#define BN_EPS 1e-5f

typedef short short8 __attribute__((ext_vector_type(8)));
typedef float f32x4 __attribute__((ext_vector_type(4)));
typedef unsigned short ushort_t;

__device__ inline unsigned short f2bf(float x) {
    unsigned int u = __float_as_uint(x);
    unsigned int r = (u + 0x7fffu + ((u >> 16) & 1u)) >> 16;   // round-to-nearest-even
    return (unsigned short)r;
}
__device__ inline float bf2f(unsigned short h) {
    return __uint_as_float(((unsigned int)h) << 16);
}

// ---------------- pooling: img(28x28) -> x2(14x14) -> x1(7x7); blocks 0-2 also zero bn accum ----------------
__global__ void pool_kernel(const float* __restrict__ img,
                            float* __restrict__ x2, float* __restrict__ x1,
                            float* __restrict__ bnp_base) {
    __shared__ float s_img[784];
    __shared__ float s_x2[196];
    int b = blockIdx.x;
    if (b < 3) {  // zero sum/sq accumulators for the 3 branches (ws is poisoned)
        bnp_base[b * 512 + threadIdx.x] = 0.f;
        bnp_base[b * 512 + 256 + threadIdx.x] = 0.f;
    }
    const float* im = img + b * 784;
    for (int i = threadIdx.x; i < 784; i += 256) s_img[i] = im[i];
    __syncthreads();
    for (int idx = threadIdx.x; idx < 196; idx += 256) {
        int i = idx / 14, j = idx % 14;
        float v = 0.25f * (s_img[(2*i)*28 + 2*j]     + s_img[(2*i)*28 + 2*j + 1] +
                           s_img[(2*i+1)*28 + 2*j]   + s_img[(2*i+1)*28 + 2*j + 1]);
        s_x2[idx] = v;
        x2[b*196 + idx] = v;
    }
    __syncthreads();
    for (int idx = threadIdx.x; idx < 49; idx += 256) {
        int i = idx / 7, j = idx % 7;
        float v = 0.25f * (s_x2[(2*i)*14 + 2*j]     + s_x2[(2*i)*14 + 2*j + 1] +
                           s_x2[(2*i+1)*14 + 2*j]   + s_x2[(2*i+1)*14 + 2*j + 1]);
        x1[b*49 + idx] = v;
    }
}

// ---------------- conv (1->128ch, stride1, VALID) + relu, split-bf16 out [b][pos][c], BN stats ----------------
template<int IH, int IW, int KS, int OH, int OW>
__global__ __launch_bounds__(256) void conv_split_kernel(
        const float* __restrict__ in, const float* __restrict__ w,
        const float* __restrict__ bias,
        ushort_t* __restrict__ yh, ushort_t* __restrict__ yl,
        float* __restrict__ bnp) {
    constexpr int KK = KS * KS;
    constexpr int OS = OH * OW;
    __shared__ float s_img[IH * IW];
    __shared__ float s_w[128 * KK];
    __shared__ float s_red[256];
    int b = blockIdx.x, tid = threadIdx.x;
    const float* ip = in + b * IH * IW;
    for (int i = tid; i < IH * IW; i += 256) s_img[i] = ip[i];
    for (int i = tid; i < 128 * KK; i += 256) s_w[i] = w[i];
    __syncthreads();
    int c = tid & 127, half = tid >> 7;
    float bias_c = bias[c];
    float bsum = 0.f, bsq = 0.f;
    for (int r = half; r < OH; r += 2) {
        float acc[OW];
        #pragma unroll
        for (int j = 0; j < OW; ++j) acc[j] = bias_c;
        for (int u = 0; u < KS; ++u) {
            float rg[OW + KS - 1];
            #pragma unroll
            for (int j = 0; j < OW + KS - 1; ++j) rg[j] = s_img[(r + u) * IW + j];
            #pragma unroll
            for (int v = 0; v < KS; ++v) {
                float wv = s_w[c * KK + u * KS + v];
                #pragma unroll
                for (int j = 0; j < OW; ++j) acc[j] += wv * rg[j + v];
            }
        }
        #pragma unroll
        for (int j = 0; j < OW; ++j) {
            float val = fmaxf(acc[j], 0.f);
            bsum += val; bsq += val * val;
            unsigned short h = f2bf(val);
            unsigned short lo = f2bf(val - bf2f(h));
            int oidx = ((b * OS) + r * OW + j) * 128 + c;
            yh[oidx] = h; yl[oidx] = lo;
        }
    }
    s_red[tid] = bsum; __syncthreads();
    if (tid < 128) atomicAdd(&bnp[c], s_red[tid] + s_red[tid + 128]);
    __syncthreads();
    s_red[tid] = bsq; __syncthreads();
    if (tid < 128) atomicAdd(&bnp[128 + c], s_red[tid] + s_red[tid + 128]);
}

// ---------------- finalize BN: scale/shift per channel, 3 branches ----------------
__global__ void bn_final_kernel(float* __restrict__ bnp_base) {
    int br = blockIdx.x;
    float* bnp = bnp_base + br * 512;
    float N = (br == 0) ? 6400.f : ((br == 1) ? 25600.f : 102400.f);
    int c = threadIdx.x;  // 128
    float mean = bnp[c] / N;
    float var = bnp[128 + c] / N - mean * mean;
    float inv = rsqrtf(var + BN_EPS);
    bnp[256 + c] = inv;
    bnp[384 + c] = -mean * inv;
}

// ---------------- weight transform (all branches): W[ch][c][uv]*scale_c -> split bf16 [uv][ch][c] ----------------
__global__ void wtrans_all_kernel(const float* __restrict__ w1, const float* __restrict__ w2,
                                  const float* __restrict__ w3, const float* __restrict__ bnp_base,
                                  ushort_t* __restrict__ wh1, ushort_t* __restrict__ wl1,
                                  ushort_t* __restrict__ wh2, ushort_t* __restrict__ wl2,
                                  ushort_t* __restrict__ wh3, ushort_t* __restrict__ wl3) {
    int blk = blockIdx.x;
    const float* w; const float* bnp; ushort_t* wh; ushort_t* wl; int KK;
    if (blk < 1152)      { w = w1; bnp = bnp_base;        wh = wh1; wl = wl1; KK = 9;  }
    else if (blk < 4352) { w = w2; bnp = bnp_base + 512;  wh = wh2; wl = wl2; KK = 25; blk -= 1152; }
    else                 { w = w3; bnp = bnp_base + 1024; wh = wh3; wl = wl3; KK = 81; blk -= 4352; }
    int idx = blk * 256 + threadIdx.x;
    int c = idx & 127, ch = (idx >> 7) & 255, uv = idx >> 15;
    float val = w[((ch << 7) + c) * KK + uv] * bnp[256 + c];
    unsigned short h = f2bf(val);
    unsigned short lo = f2bf(val - bf2f(h));
    wh[idx] = h; wl[idx] = lo;
}

// ---------------- fold BN shift into per-channel bias (all branches) ----------------
__global__ void biasfold_all_kernel(const float* __restrict__ w1, const float* __restrict__ w2,
                                    const float* __restrict__ w3, const float* __restrict__ bnp_base,
                                    const float* __restrict__ pb1, const float* __restrict__ pb2,
                                    const float* __restrict__ pb3,
                                    float* __restrict__ b1, float* __restrict__ b2, float* __restrict__ b3) {
    int br = blockIdx.x >> 8, ch = blockIdx.x & 255, tid = threadIdx.x;  // 128 threads, c = tid
    const float* w  = (br == 0) ? w1  : (br == 1) ? w2  : w3;
    const float* pb = (br == 0) ? pb1 : (br == 1) ? pb2 : pb3;
    float* bf       = (br == 0) ? b1  : (br == 1) ? b2  : b3;
    int KK          = (br == 0) ? 9   : (br == 1) ? 25  : 81;
    const float* bnp = bnp_base + br * 512;
    const float* wrow = w + (ch * 128 + tid) * KK;
    float s = 0.f;
    for (int uv = 0; uv < KK; ++uv) s += wrow[uv];
    s *= bnp[384 + tid];
    for (int off = 32; off; off >>= 1) s += __shfl_down(s, off);
    __shared__ float r2[2];
    if ((tid & 63) == 0) r2[tid >> 6] = s;
    __syncthreads();
    if (tid == 0) bf[ch] = pb[ch] + r2[0] + r2[1];
}

// ---------------- primary-caps conv as split-bf16 MFMA GEMM ----------------
// 64(M) x 64(N) block tile, 4 waves as 2x2 (each 32x32 = 2x2 of 16x16), BK=32.
// LDS pitch 72 halves: writes conflict-free (bank 4(r+c) mod 32, balanced), reads 2-way (free).
template<int S, int WO, int IHg, int IWg, int KS>
__global__ __launch_bounds__(256, 4) void prim_gemm_mfma(
        const ushort_t* __restrict__ yh, const ushort_t* __restrict__ yl,
        const ushort_t* __restrict__ wh, const ushort_t* __restrict__ wl,
        const float* __restrict__ biasf, float* __restrict__ p) {
    constexpr int AP = 72;
    __shared__ ushort_t Ash[64 * AP], Asl[64 * AP];
    __shared__ ushort_t Bsh[64 * AP], Bsl[64 * AP];
    int tid = threadIdx.x;
    int bm = blockIdx.x * 64, ch0 = blockIdx.y * 64;
    // staging: thread -> (row = tid>>2 of 64, 8-half chunk = (tid&3)*8 of 32)
    int arow = tid >> 2;
    int cpart = (tid & 3) * 8;
    int m0 = bm + arow;
    int b0 = m0 / S, s0 = m0 % S;
    int abase = ((b0 * IHg + 2 * (s0 / WO)) * IWg + 2 * (s0 % WO)) * 128 + cpart;
    int bbase = (ch0 + arow) * 128 + cpart;
    int wLidx = arow * AP + cpart;
    // compute roles
    int lane = tid & 63, wid = tid >> 6;
    int wm = wid & 1, wn = wid >> 1;
    int quad = lane >> 4, l16 = lane & 15;
    int aoffL[2], boffL[2];
    #pragma unroll
    for (int mi = 0; mi < 2; ++mi) aoffL[mi] = (wm * 32 + mi * 16 + l16) * AP + quad * 8;
    #pragma unroll
    for (int ni = 0; ni < 2; ++ni) boffL[ni] = (wn * 32 + ni * 16 + l16) * AP + quad * 8;
    f32x4 acc[2][2];
    #pragma unroll
    for (int mi = 0; mi < 2; ++mi)
        #pragma unroll
        for (int ni = 0; ni < 2; ++ni)
            acc[mi][ni] = (f32x4){0.f, 0.f, 0.f, 0.f};

    for (int u = 0; u < KS; ++u) {
        for (int v = 0; v < KS; ++v) {
            int aoff = (u * IWg + v) * 128;
            int boff = (u * KS + v) * 32768;
            for (int cs = 0; cs < 128; cs += 32) {
                int4 a4h = *reinterpret_cast<const int4*>(yh + abase + aoff + cs);
                int4 a4l = *reinterpret_cast<const int4*>(yl + abase + aoff + cs);
                int4 b4h = *reinterpret_cast<const int4*>(wh + bbase + boff + cs);
                int4 b4l = *reinterpret_cast<const int4*>(wl + bbase + boff + cs);
                __syncthreads();
                *reinterpret_cast<int4*>(&Ash[wLidx]) = a4h;
                *reinterpret_cast<int4*>(&Asl[wLidx]) = a4l;
                *reinterpret_cast<int4*>(&Bsh[wLidx]) = b4h;
                *reinterpret_cast<int4*>(&Bsl[wLidx]) = b4l;
                __syncthreads();
                short8 ah[2], al[2], bh[2], bl[2];
                #pragma unroll
                for (int mi = 0; mi < 2; ++mi) {
                    ah[mi] = *reinterpret_cast<const short8*>(&Ash[aoffL[mi]]);
                    al[mi] = *reinterpret_cast<const short8*>(&Asl[aoffL[mi]]);
                }
                #pragma unroll
                for (int ni = 0; ni < 2; ++ni) {
                    bh[ni] = *reinterpret_cast<const short8*>(&Bsh[boffL[ni]]);
                    bl[ni] = *reinterpret_cast<const short8*>(&Bsl[boffL[ni]]);
                }
                #pragma unroll
                for (int mi = 0; mi < 2; ++mi)
                    #pragma unroll
                    for (int ni = 0; ni < 2; ++ni) {
                        acc[mi][ni] = __builtin_amdgcn_mfma_f32_16x16x32_bf16(ah[mi], bh[ni], acc[mi][ni], 0, 0, 0);
                        acc[mi][ni] = __builtin_amdgcn_mfma_f32_16x16x32_bf16(al[mi], bh[ni], acc[mi][ni], 0, 0, 0);
                        acc[mi][ni] = __builtin_amdgcn_mfma_f32_16x16x32_bf16(ah[mi], bl[ni], acc[mi][ni], 0, 0, 0);
                    }
            }
        }
    }
    float bv[2];
    #pragma unroll
    for (int ni = 0; ni < 2; ++ni) bv[ni] = biasf[ch0 + wn * 32 + ni * 16 + l16];
    #pragma unroll
    for (int mi = 0; mi < 2; ++mi)
        #pragma unroll
        for (int ni = 0; ni < 2; ++ni) {
            int col = ch0 + wn * 32 + ni * 16 + l16;
            #pragma unroll
            for (int reg = 0; reg < 4; ++reg) {
                int row = bm + wm * 32 + mi * 16 + quad * 4 + reg;
                p[(size_t)row * 256 + col] = acc[mi][ni][reg] + bv[ni];
            }
        }
}

// ---------------- squash primary caps (all branches): p(B*S,256) -> u(B,32*S,8) ----------------
// consecutive lanes vary o (contiguous 128B reads); float4 writes pair into full lines via lane i / i+32
__global__ void squash_all_kernel(const float* __restrict__ p1, const float* __restrict__ p2,
                                  const float* __restrict__ p3,
                                  float* __restrict__ u1, float* __restrict__ u2,
                                  float* __restrict__ u3) {
    int blk = blockIdx.x;
    const float* p; float* u; int S;
    if (blk < 128)      { p = p1; u = u1; S = 4; }
    else if (blk < 416) { p = p2; u = u2; S = 9;  blk -= 128; }
    else                { p = p3; u = u3; S = 36; blk -= 416; }
    int idx = blk * 256 + threadIdx.x;   // over 256*S*32, o innermost
    int o = idx & 31, rest = idx >> 5;
    int s = rest % S, b = rest / S;
    const float* pp = p + (size_t)(b * S + s) * 256 + o;
    float t[8]; float sn = 0.f;
    #pragma unroll
    for (int i = 0; i < 8; ++i) { t[i] = pp[i * 32]; sn += t[i] * t[i]; }
    float f = sn / ((1.f + sn) * sqrtf(sn + SQ_EPS));
    float* up = u + (size_t)(b * (32 * S) + o * S + s) * 8;
    float4 w0 = {t[0] * f, t[1] * f, t[2] * f, t[3] * f};
    float4 w1 = {t[4] * f, t[5] * f, t[6] * f, t[7] * f};
    *reinterpret_cast<float4*>(up) = w0;
    *reinterpret_cast<float4*>(up + 4) = w1;
}

// ---------------- dynamic routing (3 iters), all branches; priors cached in LDS (bf16) ----------------
#define RMAX 1152
__global__ __launch_bounds__(256) void routing_all_kernel(
        const float* __restrict__ u1, const float* __restrict__ u2, const float* __restrict__ u3,
        const float* __restrict__ w1, const float* __restrict__ w2, const float* __restrict__ w3,
        float* __restrict__ l1, float* __restrict__ l2, float* __restrict__ l3) {
    int n = blockIdx.x, b = blockIdx.y, br = blockIdx.z;
    const float* u; const float* rw; float* lens; int R;
    if (br == 0)      { u = u1; rw = w1; lens = l1; R = 128; }
    else if (br == 1) { u = u2; rw = w2; lens = l2; R = 288; }
    else              { u = u3; rw = w3; lens = l3; R = 1152; }
    __shared__ ushort_t pri[RMAX * 17];
    __shared__ float blog[RMAX];
    __shared__ float red[4 * 16];
    __shared__ float vsh[16];
    __shared__ float sred[4];
    int tid = threadIdx.x, lane = tid & 63, wv = tid >> 6;
    for (int r = tid; r < R; r += 256) {
        const float4* up = (const float4*)(u + ((size_t)b * R + r) * 8);
        float4 ua = up[0], ub = up[1];
        float uu[8] = {ua.x, ua.y, ua.z, ua.w, ub.x, ub.y, ub.z, ub.w};
        const float4* wp = (const float4*)(rw + ((size_t)n * R + r) * 128);
        float po[16] = {};
        #pragma unroll
        for (int i = 0; i < 8; ++i) {
            #pragma unroll
            for (int o4 = 0; o4 < 4; ++o4) {
                float4 w4 = wp[i * 4 + o4];
                po[o4 * 4 + 0] += uu[i] * w4.x;
                po[o4 * 4 + 1] += uu[i] * w4.y;
                po[o4 * 4 + 2] += uu[i] * w4.z;
                po[o4 * 4 + 3] += uu[i] * w4.w;
            }
        }
        #pragma unroll
        for (int o = 0; o < 16; ++o) pri[r * 17 + o] = f2bf(po[o]);
        blog[r] = 0.f;
    }
    __syncthreads();
    float v[16];
    for (int it = 0; it < 3; ++it) {
        float lmax = -1e30f;
        for (int r = tid; r < R; r += 256) lmax = fmaxf(lmax, blog[r]);
        for (int off = 32; off; off >>= 1) lmax = fmaxf(lmax, __shfl_down(lmax, off));
        if (lane == 0) sred[wv] = lmax;
        __syncthreads();
        float mx = fmaxf(fmaxf(sred[0], sred[1]), fmaxf(sred[2], sred[3]));
        __syncthreads();
        float lsum = 0.f;
        for (int r = tid; r < R; r += 256) lsum += expf(blog[r] - mx);
        for (int off = 32; off; off >>= 1) lsum += __shfl_down(lsum, off);
        if (lane == 0) sred[wv] = lsum;
        __syncthreads();
        float inv = 1.f / (sred[0] + sred[1] + sred[2] + sred[3]);
        float sacc[16] = {};
        for (int r = tid; r < R; r += 256) {
            float c = expf(blog[r] - mx) * inv;
            #pragma unroll
            for (int o = 0; o < 16; ++o) sacc[o] += c * bf2f(pri[r * 17 + o]);
        }
        #pragma unroll
        for (int o = 0; o < 16; ++o) {
            float xv = sacc[o];
            for (int off = 32; off; off >>= 1) xv += __shfl_down(xv, off);
            if (lane == 0) red[wv * 16 + o] = xv;
        }
        __syncthreads();
        if (tid < 16) vsh[tid] = red[tid] + red[16 + tid] + red[32 + tid] + red[48 + tid];
        __syncthreads();
        if (tid == 0) {
            float sn = 0.f;
            #pragma unroll
            for (int o = 0; o < 16; ++o) sn += vsh[o] * vsh[o];
            float f = sn / ((1.f + sn) * sqrtf(sn + SQ_EPS));
            #pragma unroll
            for (int o = 0; o < 16; ++o) vsh[o] *= f;
        }
        __syncthreads();
        #pragma unroll
        for (int o = 0; o < 16; ++o) v[o] = vsh[o];
        if (it < 2) {
            for (int r = tid; r < R; r += 256) {
                float dot = 0.f;
                #pragma unroll
                for (int o = 0; o < 16; ++o) dot += bf2f(pri[r * 17 + o]) * v[o];
                blog[r] += dot;
            }
            __syncthreads();
        }
    }
    if (tid == 0) {
        float sn = 0.f;
        #pragma unroll
        for (int o = 0; o < 16; ++o) sn += v[o] * v[o];
        lens[b * 10 + n] = sqrtf(sn + SQ_EPS);
    }
}

// ---------------- final: softmax over classes of l1+l2+l3 ----------------
__global__ void final_softmax_kernel(const float* __restrict__ l1, const float* __restrict__ l2,
                                     const float* __restrict__ l3, float* __restrict__ out) {
    int b = threadIdx.x;
    float v[10]; float mx = -1e30f;
    #pragma unroll
    for (int n = 0; n < 10; ++n) {
        v[n] = l1[b * 10 + n] + l2[b * 10 + n] + l3[b * 10 + n];
        mx = fmaxf(mx, v[n]);
    }
    float s = 0.f;
    #pragma unroll
    for (int n = 0; n < 10; ++n) { v[n] = expf(v[n] - mx); s += v[n]; }
    float inv = 1.f / s;
    #pragma unroll
    for (int n = 0; n < 10; ++n) out[b * 10 + n] = v[n] * inv;
}

extern "C" void kernel_launch(void* const* d_in, const int* in_sizes, int n_in,
                              void* d_out, int out_size, void* d_ws, size_t ws_size,
                              hipStream_t stream) {
    const float* x   = (const float*)d_in[0];
    const float* c1w = (const float*)d_in[1];
    const float* c1b = (const float*)d_in[2];
    const float* p1w = (const float*)d_in[3];
    const float* p1b = (const float*)d_in[4];
    const float* d1w = (const float*)d_in[5];
    const float* c2w = (const float*)d_in[6];
    const float* c2b = (const float*)d_in[7];
    const float* p2w = (const float*)d_in[8];
    const float* p2b = (const float*)d_in[9];
    const float* d2w = (const float*)d_in[10];
    const float* c3w = (const float*)d_in[11];
    const float* c3b = (const float*)d_in[12];
    const float* p3w = (const float*)d_in[13];
    const float* p3b = (const float*)d_in[14];
    const float* d3w = (const float*)d_in[15];

    float* ws = (float*)d_ws;
    // region layout (float units) — total 23,403,520 floats = 93.6 MB
    float* x2    = ws + 0;          // 50176
    float* x1    = ws + 50176;      // 12544
    float* yh1f  = ws + 62720;      // 409600   (819200 halves)  [aliased by u1 later]
    float* yl1f  = ws + 472320;     // 409600
    float* yh2f  = ws + 881920;     // 1638400  [aliased by u2 later]
    float* yl2f  = ws + 2520320;    // 1638400
    float* yh3f  = ws + 4158720;    // 6553600  [aliased by u3 later]
    float* yl3f  = ws + 10712320;   // 6553600
    float* wh1f  = ws + 17265920;   // 147456
    float* wl1f  = ws + 17413376;   // 147456
    float* wh2f  = ws + 17560832;   // 409600
    float* wl2f  = ws + 17970432;   // 409600
    float* wh3f  = ws + 18380032;   // 1327104  [aliased by p2 later]
    float* wl3f  = ws + 19707136;   // 1327104  [aliased by p1 later]
    float* p3    = ws + 21034240;   // 2359296
    float* bnp1  = ws + 23393536;   // 512 (x3: bnp2, bnp3 follow)
    float* bias1 = ws + 23395072;   // 256
    float* bias2 = ws + 23395328;   // 256
    float* bias3 = ws + 23395584;   // 256
    float* l1    = ws + 23395840;   // 2560
    float* l2    = ws + 23398400;   // 2560
    float* l3    = ws + 23400960;   // 2560

    ushort_t* yh1 = (ushort_t*)yh1f; ushort_t* yl1 = (ushort_t*)yl1f;
    ushort_t* yh2 = (ushort_t*)yh2f; ushort_t* yl2 = (ushort_t*)yl2f;
    ushort_t* yh3 = (ushort_t*)yh3f; ushort_t* yl3 = (ushort_t*)yl3f;
    ushort_t* wh1 = (ushort_t*)wh1f; ushort_t* wl1 = (ushort_t*)wl1f;
    ushort_t* wh2 = (ushort_t*)wh2f; ushort_t* wl2 = (ushort_t*)wl2f;
    ushort_t* wh3 = (ushort_t*)wh3f; ushort_t* wl3 = (ushort_t*)wl3f;
    // aliases (safe by stream ordering):
    float* u1 = yh1f;   // written after gemm1 reads yh1
    float* u2 = yh2f;
    float* u3 = yh3f;
    float* p2 = wh3f;   // written after gemm3 reads wh3
    float* p1 = wl3f;

    pool_kernel<<<256, 256, 0, stream>>>(x, x2, x1, bnp1);

    conv_split_kernel<7, 7, 3, 5, 5><<<256, 256, 0, stream>>>(x1, c1w, c1b, yh1, yl1, bnp1);
    conv_split_kernel<14, 14, 5, 10, 10><<<256, 256, 0, stream>>>(x2, c2w, c2b, yh2, yl2, bnp1 + 512);
    conv_split_kernel<28, 28, 9, 20, 20><<<256, 256, 0, stream>>>(x, c3w, c3b, yh3, yl3, bnp1 + 1024);

    bn_final_kernel<<<3, 128, 0, stream>>>(bnp1);

    wtrans_all_kernel<<<14720, 256, 0, stream>>>(p1w, p2w, p3w, bnp1,
                                                 wh1, wl1, wh2, wl2, wh3, wl3);
    biasfold_all_kernel<<<768, 128, 0, stream>>>(p1w, p2w, p3w, bnp1,
                                                 p1b, p2b, p3b, bias1, bias2, bias3);

    // gemm3 first: afterwards wh3/wl3 are dead and reused for p2/p1
    prim_gemm_mfma<36, 6, 20, 20, 9><<<dim3(144, 4), 256, 0, stream>>>(yh3, yl3, wh3, wl3, bias3, p3);
    prim_gemm_mfma<9, 3, 10, 10, 5><<<dim3(36, 4), 256, 0, stream>>>(yh2, yl2, wh2, wl2, bias2, p2);
    prim_gemm_mfma<4, 2, 5, 5, 3><<<dim3(16, 4), 256, 0, stream>>>(yh1, yl1, wh1, wl1, bias1, p1);

    squash_all_kernel<<<1568, 256, 0, stream>>>(p1, p2, p3, u1, u2, u3);

    routing_all_kernel<<<dim3(10, 256, 3), 256, 0, stream>>>(u1, u2, u3, d1w, d2w, d3w, l1, l2, l3);

    final_softmax_kernel<<<1, 256, 0, stream>>>(l1, l2, l3, (float*)d_out);
}